// Round 1
// baseline (389.327 us; speedup 1.0000x reference)
//
#include <hip/hip_runtime.h>
#include <hip/hip_bf16.h>

#define TPB 256

// ---------- workspace layout ----------
// [0,32)        double acc[4]   : 0=depth_sum, 1=epi_sum, 2=normal_sum
// [64,320)      float  F[6][9]  : fundamental matrices
// [512, 512+N*3*4)  float normals[N][3]
// [CAND_OFF, ...)   float cand_d2[S*10][N] ; int cand_idx[S*10][N]
#define F_OFF     64
#define NRM_OFF   512

__device__ inline double waveReduce(double v) {
#pragma unroll
    for (int off = 32; off > 0; off >>= 1)
        v += __shfl_down(v, off, 64);
    return v;
}

// ---------- setup: zero accumulators, compute 6 fundamental matrices ----------
__device__ inline void inv3_mul_neg(const float A[9], const float b[3], float out[3]) {
    // out = -inv(A) @ b
    float c00 =  A[4]*A[8] - A[5]*A[7];
    float c01 = -(A[3]*A[8] - A[5]*A[6]);
    float c02 =  A[3]*A[7] - A[4]*A[6];
    float det = A[0]*c00 + A[1]*c01 + A[2]*c02;
    float i00 = c00,  i01 = -(A[1]*A[8]-A[2]*A[7]), i02 =  (A[1]*A[5]-A[2]*A[4]);
    float i10 = c01,  i11 =  (A[0]*A[8]-A[2]*A[6]), i12 = -(A[0]*A[5]-A[2]*A[3]);
    float i20 = c02,  i21 = -(A[0]*A[7]-A[1]*A[6]), i22 =  (A[0]*A[4]-A[1]*A[3]);
    float inv_det = 1.0f / det;
    out[0] = -(i00*b[0] + i01*b[1] + i02*b[2]) * inv_det;
    out[1] = -(i10*b[0] + i11*b[1] + i12*b[2]) * inv_det;
    out[2] = -(i20*b[0] + i21*b[1] + i22*b[2]) * inv_det;
}

__global__ void setup_kernel(const float* __restrict__ V, float* __restrict__ Fm,
                             double* __restrict__ acc) {
    if (threadIdx.x != 0 || blockIdx.x != 0) return;
    acc[0] = 0.0; acc[1] = 0.0; acc[2] = 0.0; acc[3] = 0.0;

    // per-view A (3x3 upper-left) and camera center C = -inv(A) b
    float A[4][9], C[4][3];
    for (int v = 0; v < 4; ++v) {
        const float* Vb = V + 16 * v;
        float b[3];
        for (int r = 0; r < 3; ++r) {
            A[v][3*r+0] = Vb[4*r+0];
            A[v][3*r+1] = Vb[4*r+1];
            A[v][3*r+2] = Vb[4*r+2];
            b[r] = Vb[4*r+3];
        }
        inv3_mul_neg(A[v], b, C[v]);
    }
    int pi = 0;
    for (int i = 0; i < 4; ++i) {
        for (int j = i + 1; j < 4; ++j) {
            float t0 = C[j][0] - C[i][0];
            float t1 = C[j][1] - C[i][1];
            float t2 = C[j][2] - C[i][2];
            // R = A_j @ A_i^T
            float R[9];
            for (int r = 0; r < 3; ++r)
                for (int c = 0; c < 3; ++c)
                    R[3*r+c] = A[j][3*r+0]*A[i][3*c+0] + A[j][3*r+1]*A[i][3*c+1]
                             + A[j][3*r+2]*A[i][3*c+2];
            // F = skew(t) @ R ; skew = [[0,-t2,t1],[t2,0,-t0],[-t1,t0,0]]
            float* F = Fm + 9 * pi;
            for (int c = 0; c < 3; ++c) {
                F[0+c] = -t2 * R[3+c] + t1 * R[6+c];
                F[3+c] =  t2 * R[0+c] - t0 * R[6+c];
                F[6+c] = -t1 * R[0+c] + t0 * R[3+c];
            }
            ++pi;
        }
    }
}

// ---------- per-point: normals, depth loss, epipolar loss ----------
__global__ void perpoint_kernel(const float* __restrict__ pos,
                                const float* __restrict__ rot,
                                const float* __restrict__ opac,
                                const float* __restrict__ V,
                                const float* __restrict__ Fm,
                                float* __restrict__ normals,
                                double* __restrict__ acc, int N) {
    int n = blockIdx.x * TPB + threadIdx.x;
    double dsum = 0.0, esum = 0.0;
    if (n < N) {
        float x = pos[3*n], y = pos[3*n+1], z = pos[3*n+2];
        float o = opac[n];
        float qw = rot[4*n], qx = rot[4*n+1], qy = rot[4*n+2], qz = rot[4*n+3];
        float qinv = 1.0f / sqrtf(qw*qw + qx*qx + qy*qy + qz*qz);
        qw *= qinv; qx *= qinv; qy *= qinv; qz *= qinv;
        float nx = 2.0f*(qx*qz + qw*qy);
        float ny = 2.0f*(qy*qz - qw*qx);
        float nz = 1.0f - 2.0f*(qx*qx + qy*qy);
        normals[3*n] = nx; normals[3*n+1] = ny; normals[3*n+2] = nz;

        float czv[4], pxv[4], pyv[4];
#pragma unroll
        for (int b = 0; b < 4; ++b) {
            const float* Vb = V + 16*b;
            float cx = Vb[0]*x + Vb[1]*y + Vb[2]*z  + Vb[3];
            float cy = Vb[4]*x + Vb[5]*y + Vb[6]*z  + Vb[7];
            float cz = Vb[8]*x + Vb[9]*y + Vb[10]*z + Vb[11];
            czv[b] = cz;
            float zc = fmaxf(cz, 1e-8f);
            pxv[b] = cx / zc;
            pyv[b] = cy / zc;
        }
        dsum = (double)(fabsf(czv[0]*o - czv[1]*o) + fabsf(czv[1]*o - czv[2]*o)
                      + fabsf(czv[2]*o - czv[3]*o));
        int pi = 0;
#pragma unroll
        for (int a = 0; a < 4; ++a) {
#pragma unroll
            for (int b2 = a + 1; b2 < 4; ++b2) {
                const float* F = Fm + 9*pi; ++pi;
                float x1 = pxv[a], y1 = pyv[a];
                float x2 = pxv[b2], y2 = pyv[b2];
                float l0 = F[0]*x1 + F[1]*y1 + F[2];
                float l1 = F[3]*x1 + F[4]*y1 + F[5];
                float l2 = F[6]*x1 + F[7]*y1 + F[8];
                float err = fabsf(x2*l0 + y2*l1 + l2);
                float nrm = sqrtf(l0*l0 + l1*l1) + 1e-8f;
                esum += (double)((err / nrm) * o);
            }
        }
    }
    // block reduce
    dsum = waveReduce(dsum);
    esum = waveReduce(esum);
    __shared__ double sred[2][4];
    int lane = threadIdx.x & 63, w = threadIdx.x >> 6;
    if (lane == 0) { sred[0][w] = dsum; sred[1][w] = esum; }
    __syncthreads();
    if (threadIdx.x == 0) {
        double a0 = 0, a1 = 0;
        for (int k = 0; k < 4; ++k) { a0 += sred[0][k]; a1 += sred[1][k]; }
        atomicAdd(&acc[0], a0);
        atomicAdd(&acc[1], a1);
    }
}

// ---------- KNN pass 1: per (i, j-split) top-10 ----------
__global__ void knn_pass1(const float* __restrict__ pos,
                          float* __restrict__ cand_d2, int* __restrict__ cand_idx,
                          int N, int rangeLen) {
    int i = blockIdx.x * TPB + threadIdx.x;
    int s = blockIdx.y;
    int j0 = s * rangeLen;
    int j1 = j0 + rangeLen;

    __shared__ float sx[TPB], sy[TPB], sz[TPB];

    float px = 0.f, py = 0.f, pz = 0.f;
    if (i < N) { px = pos[3*i]; py = pos[3*i+1]; pz = pos[3*i+2]; }

    float bd[10]; int bi[10];
#pragma unroll
    for (int k = 0; k < 10; ++k) { bd[k] = 3.4e38f; bi[k] = -1; }

    for (int t = j0; t < j1; t += TPB) {
        int tj = t + threadIdx.x;
        int cj = tj < N ? tj : (N - 1);
        sx[threadIdx.x] = pos[3*cj];
        sy[threadIdx.x] = pos[3*cj+1];
        sz[threadIdx.x] = pos[3*cj+2];
        __syncthreads();
#pragma unroll 8
        for (int jj = 0; jj < TPB; ++jj) {
            int j = t + jj;
            float dx = px - sx[jj];
            float dy = py - sy[jj];
            float dz = pz - sz[jj];
            float d2 = dx*dx + dy*dy + dz*dz;
            if (d2 < bd[9] && j != i) {
                float cd = d2; int ci = j;
#pragma unroll
                for (int k = 0; k < 10; ++k) {
                    bool sw = cd < bd[k];
                    float td = sw ? bd[k] : cd;  int ti = sw ? bi[k] : ci;
                    bd[k]    = sw ? cd   : bd[k]; bi[k] = sw ? ci   : bi[k];
                    cd = td; ci = ti;
                }
            }
        }
        __syncthreads();
    }
    if (i < N) {
#pragma unroll
        for (int k = 0; k < 10; ++k) {
            cand_d2 [(size_t)(s*10 + k) * N + i] = bd[k];
            cand_idx[(size_t)(s*10 + k) * N + i] = bi[k];
        }
    }
}

// ---------- KNN merge + normal loss ----------
__global__ void knn_merge(const float* __restrict__ cand_d2,
                          const int* __restrict__ cand_idx,
                          const float* __restrict__ normals,
                          const float* __restrict__ opac,
                          double* __restrict__ acc, int N, int S) {
    int i = blockIdx.x * TPB + threadIdx.x;
    double nsum = 0.0;
    if (i < N) {
        float bd[10]; int bi[10];
#pragma unroll
        for (int k = 0; k < 10; ++k) { bd[k] = 3.4e38f; bi[k] = -1; }
        for (int s = 0; s < S; ++s) {
            for (int k = 0; k < 10; ++k) {
                float d = cand_d2 [(size_t)(s*10 + k) * N + i];
                int   id = cand_idx[(size_t)(s*10 + k) * N + i];
                if (d < bd[9] && id >= 0) {
                    float cd = d; int ci = id;
#pragma unroll
                    for (int k2 = 0; k2 < 10; ++k2) {
                        bool sw = cd < bd[k2];
                        float td = sw ? bd[k2] : cd;  int ti = sw ? bi[k2] : ci;
                        bd[k2]   = sw ? cd    : bd[k2]; bi[k2] = sw ? ci   : bi[k2];
                        cd = td; ci = ti;
                    }
                }
            }
        }
        float nx = normals[3*i], ny = normals[3*i+1], nz = normals[3*i+2];
        float ssum = 0.0f;
#pragma unroll
        for (int k = 0; k < 10; ++k) {
            int j = bi[k];
            float c = nx*normals[3*j] + ny*normals[3*j+1] + nz*normals[3*j+2];
            ssum += 1.0f - c;
        }
        nsum = (double)(opac[i] * (ssum * 0.1f));
    }
    nsum = waveReduce(nsum);
    __shared__ double sred[4];
    int lane = threadIdx.x & 63, w = threadIdx.x >> 6;
    if (lane == 0) sred[w] = nsum;
    __syncthreads();
    if (threadIdx.x == 0) {
        double a = 0;
        for (int k = 0; k < 4; ++k) a += sred[k];
        atomicAdd(&acc[2], a);
    }
}

// ---------- finalize ----------
__global__ void finalize_kernel(const double* __restrict__ acc, float* __restrict__ out, int N) {
    if (threadIdx.x == 0 && blockIdx.x == 0) {
        double depth_loss  = acc[0] / (3.0 * (double)N);
        double epi_loss    = acc[1] / 6.0;
        double normal_loss = acc[2] / (double)N;
        out[0] = (float)(depth_loss + epi_loss + normal_loss);
    }
}

extern "C" void kernel_launch(void* const* d_in, const int* in_sizes, int n_in,
                              void* d_out, int out_size, void* d_ws, size_t ws_size,
                              hipStream_t stream) {
    const float* pos = (const float*)d_in[0];
    const float* rot = (const float*)d_in[1];
    const float* opa = (const float*)d_in[2];
    const float* V   = (const float*)d_in[3];
    float* out = (float*)d_out;

    int N = in_sizes[0] / 3;   // 12288

    char* w = (char*)d_ws;
    double* acc    = (double*)w;
    float*  Fm     = (float*)(w + F_OFF);
    float*  nrm    = (float*)(w + NRM_OFF);
    size_t cand_off = ((size_t)NRM_OFF + (size_t)N * 3 * 4 + 255) & ~(size_t)255;

    // pick largest split count S that fits in workspace (S must divide N/256 grid cleanly)
    int S = 1;
    for (int cand = 16; cand >= 1; cand >>= 1) {
        size_t need = cand_off + (size_t)N * cand * 10 * 8;  // d2 + idx
        if (need <= ws_size && (N % cand) == 0) { S = cand; break; }
    }
    int rangeLen = N / S;
    float* cand_d2  = (float*)(w + cand_off);
    int*   cand_idx = (int*)  (w + cand_off + (size_t)N * S * 10 * 4);

    int nBlocks = (N + TPB - 1) / TPB;

    setup_kernel<<<1, 64, 0, stream>>>(V, Fm, acc);
    perpoint_kernel<<<nBlocks, TPB, 0, stream>>>(pos, rot, opa, V, Fm, nrm, acc, N);
    knn_pass1<<<dim3(nBlocks, S), TPB, 0, stream>>>(pos, cand_d2, cand_idx, N, rangeLen);
    knn_merge<<<nBlocks, TPB, 0, stream>>>(cand_d2, cand_idx, nrm, opa, acc, N, S);
    finalize_kernel<<<1, 64, 0, stream>>>(acc, out, N);
}

// Round 2
// 339.701 us; speedup vs baseline: 1.1461x; 1.1461x over previous
//
#include <hip/hip_runtime.h>
#include <hip/hip_bf16.h>

#define TPB 256
#define KNN 10
#define SPLITS 16          // j-range splits for the full pass
#define SEED_SPLITS 16
#define SEED_PER 128       // samples per seed split
#define SEED_STRIDE 6      // 16*128*6 = 12288 = N

// ---------- workspace layout ----------
// [0,64)    double acc[4] : 0=depth_sum, 1=epi_sum, 2=normal_sum
// [64,~)    float  F[6][9]
// [512,..)  float normals[N][3]
// [t_off)   float T[N]          (10th-NN upper bound)
// [bufA)    float seed_d2[160][N]  then reused as cand_d2[160][N]
// [bufB)    int   cand_idx[160][N]
#define F_OFF   64
#define NRM_OFF 512

__device__ inline double waveReduce(double v) {
#pragma unroll
    for (int off = 32; off > 0; off >>= 1)
        v += __shfl_down(v, off, 64);
    return v;
}

// ---------- setup: zero accumulators, compute 6 fundamental matrices ----------
__device__ inline void inv3_mul_neg(const float A[9], const float b[3], float out[3]) {
    float c00 =  A[4]*A[8] - A[5]*A[7];
    float c01 = -(A[3]*A[8] - A[5]*A[6]);
    float c02 =  A[3]*A[7] - A[4]*A[6];
    float det = A[0]*c00 + A[1]*c01 + A[2]*c02;
    float i00 = c00,  i01 = -(A[1]*A[8]-A[2]*A[7]), i02 =  (A[1]*A[5]-A[2]*A[4]);
    float i10 = c01,  i11 =  (A[0]*A[8]-A[2]*A[6]), i12 = -(A[0]*A[5]-A[2]*A[3]);
    float i20 = c02,  i21 = -(A[0]*A[7]-A[1]*A[6]), i22 =  (A[0]*A[4]-A[1]*A[3]);
    float inv_det = 1.0f / det;
    out[0] = -(i00*b[0] + i01*b[1] + i02*b[2]) * inv_det;
    out[1] = -(i10*b[0] + i11*b[1] + i12*b[2]) * inv_det;
    out[2] = -(i20*b[0] + i21*b[1] + i22*b[2]) * inv_det;
}

__global__ void setup_kernel(const float* __restrict__ V, float* __restrict__ Fm,
                             double* __restrict__ acc) {
    if (threadIdx.x != 0 || blockIdx.x != 0) return;
    acc[0] = 0.0; acc[1] = 0.0; acc[2] = 0.0; acc[3] = 0.0;

    float A[4][9], C[4][3];
    for (int v = 0; v < 4; ++v) {
        const float* Vb = V + 16 * v;
        float b[3];
        for (int r = 0; r < 3; ++r) {
            A[v][3*r+0] = Vb[4*r+0];
            A[v][3*r+1] = Vb[4*r+1];
            A[v][3*r+2] = Vb[4*r+2];
            b[r] = Vb[4*r+3];
        }
        inv3_mul_neg(A[v], b, C[v]);
    }
    int pi = 0;
    for (int i = 0; i < 4; ++i) {
        for (int j = i + 1; j < 4; ++j) {
            float t0 = C[j][0] - C[i][0];
            float t1 = C[j][1] - C[i][1];
            float t2 = C[j][2] - C[i][2];
            float R[9];
            for (int r = 0; r < 3; ++r)
                for (int c = 0; c < 3; ++c)
                    R[3*r+c] = A[j][3*r+0]*A[i][3*c+0] + A[j][3*r+1]*A[i][3*c+1]
                             + A[j][3*r+2]*A[i][3*c+2];
            float* F = Fm + 9 * pi;
            for (int c = 0; c < 3; ++c) {
                F[0+c] = -t2 * R[3+c] + t1 * R[6+c];
                F[3+c] =  t2 * R[0+c] - t0 * R[6+c];
                F[6+c] = -t1 * R[0+c] + t0 * R[3+c];
            }
            ++pi;
        }
    }
}

// ---------- per-point: normals, depth loss, epipolar loss ----------
__global__ void perpoint_kernel(const float* __restrict__ pos,
                                const float* __restrict__ rot,
                                const float* __restrict__ opac,
                                const float* __restrict__ V,
                                const float* __restrict__ Fm,
                                float* __restrict__ normals,
                                double* __restrict__ acc, int N) {
    int n = blockIdx.x * TPB + threadIdx.x;
    double dsum = 0.0, esum = 0.0;
    if (n < N) {
        float x = pos[3*n], y = pos[3*n+1], z = pos[3*n+2];
        float o = opac[n];
        float qw = rot[4*n], qx = rot[4*n+1], qy = rot[4*n+2], qz = rot[4*n+3];
        float qinv = 1.0f / sqrtf(qw*qw + qx*qx + qy*qy + qz*qz);
        qw *= qinv; qx *= qinv; qy *= qinv; qz *= qinv;
        float nx = 2.0f*(qx*qz + qw*qy);
        float ny = 2.0f*(qy*qz - qw*qx);
        float nz = 1.0f - 2.0f*(qx*qx + qy*qy);
        normals[3*n] = nx; normals[3*n+1] = ny; normals[3*n+2] = nz;

        float czv[4], pxv[4], pyv[4];
#pragma unroll
        for (int b = 0; b < 4; ++b) {
            const float* Vb = V + 16*b;
            float cx = Vb[0]*x + Vb[1]*y + Vb[2]*z  + Vb[3];
            float cy = Vb[4]*x + Vb[5]*y + Vb[6]*z  + Vb[7];
            float cz = Vb[8]*x + Vb[9]*y + Vb[10]*z + Vb[11];
            czv[b] = cz;
            float zc = fmaxf(cz, 1e-8f);
            pxv[b] = cx / zc;
            pyv[b] = cy / zc;
        }
        dsum = (double)(fabsf(czv[0]*o - czv[1]*o) + fabsf(czv[1]*o - czv[2]*o)
                      + fabsf(czv[2]*o - czv[3]*o));
        int pi = 0;
#pragma unroll
        for (int a = 0; a < 4; ++a) {
#pragma unroll
            for (int b2 = a + 1; b2 < 4; ++b2) {
                const float* F = Fm + 9*pi; ++pi;
                float x1 = pxv[a], y1 = pyv[a];
                float x2 = pxv[b2], y2 = pyv[b2];
                float l0 = F[0]*x1 + F[1]*y1 + F[2];
                float l1 = F[3]*x1 + F[4]*y1 + F[5];
                float l2 = F[6]*x1 + F[7]*y1 + F[8];
                float err = fabsf(x2*l0 + y2*l1 + l2);
                float nrm = sqrtf(l0*l0 + l1*l1) + 1e-8f;
                esum += (double)((err / nrm) * o);
            }
        }
    }
    dsum = waveReduce(dsum);
    esum = waveReduce(esum);
    __shared__ double sred[2][4];
    int lane = threadIdx.x & 63, w = threadIdx.x >> 6;
    if (lane == 0) { sred[0][w] = dsum; sred[1][w] = esum; }
    __syncthreads();
    if (threadIdx.x == 0) {
        double a0 = 0, a1 = 0;
        for (int k = 0; k < 4; ++k) { a0 += sred[0][k]; a1 += sred[1][k]; }
        atomicAdd(&acc[0], a0);
        atomicAdd(&acc[1], a1);
    }
}

// ---------- KNN seed: top-10 distances over a strided sample ----------
__global__ void knn_seed(const float* __restrict__ pos,
                         float* __restrict__ seed_d2, int N) {
    int i = blockIdx.x * TPB + threadIdx.x;
    int s = blockIdx.y;

    __shared__ float sx[SEED_PER], sy[SEED_PER], sz[SEED_PER];
    if (threadIdx.x < SEED_PER) {
        int j = SEED_STRIDE * (SEED_PER * s + threadIdx.x);
        if (j >= N) j = N - 1;
        sx[threadIdx.x] = pos[3*j];
        sy[threadIdx.x] = pos[3*j+1];
        sz[threadIdx.x] = pos[3*j+2];
    }
    __syncthreads();

    float px = 0.f, py = 0.f, pz = 0.f;
    if (i < N) { px = pos[3*i]; py = pos[3*i+1]; pz = pos[3*i+2]; }

    float bd[KNN];
#pragma unroll
    for (int k = 0; k < KNN; ++k) bd[k] = 3.4e38f;

#pragma unroll 4
    for (int u = 0; u < SEED_PER; ++u) {
        int j = SEED_STRIDE * (SEED_PER * s + u);
        float dx = px - sx[u];
        float dy = py - sy[u];
        float dz = pz - sz[u];
        float d2 = dx*dx + dy*dy + dz*dz;
        if (d2 < bd[KNN-1] && j != i) {
            float cd = d2;
#pragma unroll
            for (int k = 0; k < KNN; ++k) {
                bool sw = cd < bd[k];
                float td = sw ? bd[k] : cd;
                bd[k]    = sw ? cd   : bd[k];
                cd = td;
            }
        }
    }
    if (i < N) {
#pragma unroll
        for (int k = 0; k < KNN; ++k)
            seed_d2[(size_t)(s*KNN + k) * N + i] = bd[k];
    }
}

// ---------- KNN threshold: merge seed lists -> T[i] = sample 10th smallest ----------
__global__ void knn_thresh(const float* __restrict__ seed_d2,
                           float* __restrict__ T, int N) {
    int i = blockIdx.x * 64 + threadIdx.x;
    if (i >= N) return;
    float bd[KNN];
#pragma unroll
    for (int k = 0; k < KNN; ++k) bd[k] = 3.4e38f;
    for (int t = 0; t < SEED_SPLITS * KNN; ++t) {
        float d = seed_d2[(size_t)t * N + i];
        if (d < bd[KNN-1]) {
            float cd = d;
#pragma unroll
            for (int k = 0; k < KNN; ++k) {
                bool sw = cd < bd[k];
                float td = sw ? bd[k] : cd;
                bd[k]    = sw ? cd   : bd[k];
                cd = td;
            }
        }
    }
    T[i] = bd[KNN-1];
}

// ---------- KNN pass 2: full scan filtered by T[i] ----------
__global__ void knn_pass2(const float* __restrict__ pos,
                          const float* __restrict__ T,
                          float* __restrict__ cand_d2, int* __restrict__ cand_idx,
                          int N, int rangeLen) {
    int i = blockIdx.x * TPB + threadIdx.x;
    int s = blockIdx.y;
    int j0 = s * rangeLen;
    int j1 = j0 + rangeLen;

    __shared__ float sx[TPB], sy[TPB], sz[TPB];

    float px = 0.f, py = 0.f, pz = 0.f, Ti = -1.0f;
    if (i < N) { px = pos[3*i]; py = pos[3*i+1]; pz = pos[3*i+2]; Ti = T[i]; }

    float bd[KNN]; int bi[KNN];
#pragma unroll
    for (int k = 0; k < KNN; ++k) { bd[k] = 3.4e38f; bi[k] = -1; }
    float limit = Ti;   // = fminf(Ti, bd[9]); bd[9] starts at +inf

    for (int t = j0; t < j1; t += TPB) {
        int tj = t + threadIdx.x;
        int cj = tj < N ? tj : (N - 1);
        sx[threadIdx.x] = pos[3*cj];
        sy[threadIdx.x] = pos[3*cj+1];
        sz[threadIdx.x] = pos[3*cj+2];
        __syncthreads();
#pragma unroll 8
        for (int jj = 0; jj < TPB; ++jj) {
            int j = t + jj;
            float dx = px - sx[jj];
            float dy = py - sy[jj];
            float dz = pz - sz[jj];
            float d2 = dx*dx + dy*dy + dz*dz;
            if (d2 <= limit && j != i) {
                float cd = d2; int ci = j;
#pragma unroll
                for (int k = 0; k < KNN; ++k) {
                    bool sw = cd < bd[k];
                    float td = sw ? bd[k] : cd;  int ti = sw ? bi[k] : ci;
                    bd[k]    = sw ? cd   : bd[k]; bi[k] = sw ? ci   : bi[k];
                    cd = td; ci = ti;
                }
                limit = fminf(Ti, bd[KNN-1]);
            }
        }
        __syncthreads();
    }
    if (i < N) {
#pragma unroll
        for (int k = 0; k < KNN; ++k) {
            cand_d2 [(size_t)(s*KNN + k) * N + i] = bd[k];
            cand_idx[(size_t)(s*KNN + k) * N + i] = bi[k];
        }
    }
}

// ---------- KNN merge + normal loss ----------
__global__ void knn_merge(const float* __restrict__ cand_d2,
                          const int* __restrict__ cand_idx,
                          const float* __restrict__ normals,
                          const float* __restrict__ opac,
                          double* __restrict__ acc, int N) {
    int i = blockIdx.x * 64 + threadIdx.x;
    double nsum = 0.0;
    if (i < N) {
        float bd[KNN]; int bi[KNN];
#pragma unroll
        for (int k = 0; k < KNN; ++k) { bd[k] = 3.4e38f; bi[k] = -1; }
        for (int t = 0; t < SPLITS * KNN; ++t) {
            float d  = cand_d2 [(size_t)t * N + i];
            int   id = cand_idx[(size_t)t * N + i];
            if (d < bd[KNN-1] && id >= 0) {
                float cd = d; int ci = id;
#pragma unroll
                for (int k2 = 0; k2 < KNN; ++k2) {
                    bool sw = cd < bd[k2];
                    float td = sw ? bd[k2] : cd;  int ti = sw ? bi[k2] : ci;
                    bd[k2]   = sw ? cd    : bd[k2]; bi[k2] = sw ? ci   : bi[k2];
                    cd = td; ci = ti;
                }
            }
        }
        float nx = normals[3*i], ny = normals[3*i+1], nz = normals[3*i+2];
        float ssum = 0.0f;
#pragma unroll
        for (int k = 0; k < KNN; ++k) {
            int j = bi[k];
            float c = nx*normals[3*j] + ny*normals[3*j+1] + nz*normals[3*j+2];
            ssum += 1.0f - c;
        }
        nsum = (double)(opac[i] * (ssum * 0.1f));
    }
    nsum = waveReduce(nsum);
    if ((threadIdx.x & 63) == 0) atomicAdd(&acc[2], nsum);
}

// ---------- finalize ----------
__global__ void finalize_kernel(const double* __restrict__ acc, float* __restrict__ out, int N) {
    if (threadIdx.x == 0 && blockIdx.x == 0) {
        double depth_loss  = acc[0] / (3.0 * (double)N);
        double epi_loss    = acc[1] / 6.0;
        double normal_loss = acc[2] / (double)N;
        out[0] = (float)(depth_loss + epi_loss + normal_loss);
    }
}

extern "C" void kernel_launch(void* const* d_in, const int* in_sizes, int n_in,
                              void* d_out, int out_size, void* d_ws, size_t ws_size,
                              hipStream_t stream) {
    const float* pos = (const float*)d_in[0];
    const float* rot = (const float*)d_in[1];
    const float* opa = (const float*)d_in[2];
    const float* V   = (const float*)d_in[3];
    float* out = (float*)d_out;

    int N = in_sizes[0] / 3;   // 12288

    char* w = (char*)d_ws;
    double* acc = (double*)w;
    float*  Fm  = (float*)(w + F_OFF);
    float*  nrm = (float*)(w + NRM_OFF);

    size_t t_off  = ((size_t)NRM_OFF + (size_t)N * 3 * 4 + 255) & ~(size_t)255;
    size_t a_off  = (t_off + (size_t)N * 4 + 255) & ~(size_t)255;
    size_t b_off  = a_off + (size_t)SPLITS * KNN * N * 4;

    float* T        = (float*)(w + t_off);
    float* seed_d2  = (float*)(w + a_off);   // reused as cand_d2 after knn_thresh
    float* cand_d2  = (float*)(w + a_off);
    int*   cand_idx = (int*)  (w + b_off);

    int nBlocks  = (N + TPB - 1) / TPB;
    int nBlocks64 = (N + 63) / 64;
    int rangeLen = N / SPLITS;

    setup_kernel<<<1, 64, 0, stream>>>(V, Fm, acc);
    perpoint_kernel<<<nBlocks, TPB, 0, stream>>>(pos, rot, opa, V, Fm, nrm, acc, N);
    knn_seed<<<dim3(nBlocks, SEED_SPLITS), TPB, 0, stream>>>(pos, seed_d2, N);
    knn_thresh<<<nBlocks64, 64, 0, stream>>>(seed_d2, T, N);
    knn_pass2<<<dim3(nBlocks, SPLITS), TPB, 0, stream>>>(pos, T, cand_d2, cand_idx, N, rangeLen);
    knn_merge<<<nBlocks64, 64, 0, stream>>>(cand_d2, cand_idx, nrm, opa, acc, N);
    finalize_kernel<<<1, 64, 0, stream>>>(acc, out, N);
}

// Round 3
// 284.058 us; speedup vs baseline: 1.3706x; 1.1959x over previous
//
#include <hip/hip_runtime.h>
#include <hip/hip_bf16.h>

#define TPB 256
#define KNN 10
#define CSPLITS 48       // collect splits; N/CSPLITS = 256 = one LDS tile
#define CCAP 6           // candidate slots per (i, split)
#define IPT 2            // i-points per thread in collect
#define SEED_SPLITS 16
#define SEED_PER 128     // samples per seed split (M = 2048 total)
#define SEED_STRIDE 6    // 16*128*6 = 12288

#define F_OFF   64
#define NRM_OFF 512

__device__ inline double waveReduce(double v) {
#pragma unroll
    for (int off = 32; off > 0; off >>= 1)
        v += __shfl_down(v, off, 64);
    return v;
}

// ---------- setup: zero accumulators, compute 6 fundamental matrices ----------
__device__ inline void inv3_mul_neg(const float A[9], const float b[3], float out[3]) {
    float c00 =  A[4]*A[8] - A[5]*A[7];
    float c01 = -(A[3]*A[8] - A[5]*A[6]);
    float c02 =  A[3]*A[7] - A[4]*A[6];
    float det = A[0]*c00 + A[1]*c01 + A[2]*c02;
    float i00 = c00,  i01 = -(A[1]*A[8]-A[2]*A[7]), i02 =  (A[1]*A[5]-A[2]*A[4]);
    float i10 = c01,  i11 =  (A[0]*A[8]-A[2]*A[6]), i12 = -(A[0]*A[5]-A[2]*A[3]);
    float i20 = c02,  i21 = -(A[0]*A[7]-A[1]*A[6]), i22 =  (A[0]*A[4]-A[1]*A[3]);
    float inv_det = 1.0f / det;
    out[0] = -(i00*b[0] + i01*b[1] + i02*b[2]) * inv_det;
    out[1] = -(i10*b[0] + i11*b[1] + i12*b[2]) * inv_det;
    out[2] = -(i20*b[0] + i21*b[1] + i22*b[2]) * inv_det;
}

__global__ void setup_kernel(const float* __restrict__ V, float* __restrict__ Fm,
                             double* __restrict__ acc) {
    if (threadIdx.x != 0 || blockIdx.x != 0) return;
    acc[0] = 0.0; acc[1] = 0.0; acc[2] = 0.0; acc[3] = 0.0;

    float A[4][9], C[4][3];
    for (int v = 0; v < 4; ++v) {
        const float* Vb = V + 16 * v;
        float b[3];
        for (int r = 0; r < 3; ++r) {
            A[v][3*r+0] = Vb[4*r+0];
            A[v][3*r+1] = Vb[4*r+1];
            A[v][3*r+2] = Vb[4*r+2];
            b[r] = Vb[4*r+3];
        }
        inv3_mul_neg(A[v], b, C[v]);
    }
    int pi = 0;
    for (int i = 0; i < 4; ++i) {
        for (int j = i + 1; j < 4; ++j) {
            float t0 = C[j][0] - C[i][0];
            float t1 = C[j][1] - C[i][1];
            float t2 = C[j][2] - C[i][2];
            float R[9];
            for (int r = 0; r < 3; ++r)
                for (int c = 0; c < 3; ++c)
                    R[3*r+c] = A[j][3*r+0]*A[i][3*c+0] + A[j][3*r+1]*A[i][3*c+1]
                             + A[j][3*r+2]*A[i][3*c+2];
            float* F = Fm + 9 * pi;
            for (int c = 0; c < 3; ++c) {
                F[0+c] = -t2 * R[3+c] + t1 * R[6+c];
                F[3+c] =  t2 * R[0+c] - t0 * R[6+c];
                F[6+c] = -t1 * R[0+c] + t0 * R[3+c];
            }
            ++pi;
        }
    }
}

// ---------- per-point: normals, depth loss, epipolar loss ----------
__global__ void perpoint_kernel(const float* __restrict__ pos,
                                const float* __restrict__ rot,
                                const float* __restrict__ opac,
                                const float* __restrict__ V,
                                const float* __restrict__ Fm,
                                float* __restrict__ normals,
                                double* __restrict__ acc, int N) {
    int n = blockIdx.x * TPB + threadIdx.x;
    double dsum = 0.0, esum = 0.0;
    if (n < N) {
        float x = pos[3*n], y = pos[3*n+1], z = pos[3*n+2];
        float o = opac[n];
        float qw = rot[4*n], qx = rot[4*n+1], qy = rot[4*n+2], qz = rot[4*n+3];
        float qinv = 1.0f / sqrtf(qw*qw + qx*qx + qy*qy + qz*qz);
        qw *= qinv; qx *= qinv; qy *= qinv; qz *= qinv;
        float nx = 2.0f*(qx*qz + qw*qy);
        float ny = 2.0f*(qy*qz - qw*qx);
        float nz = 1.0f - 2.0f*(qx*qx + qy*qy);
        normals[3*n] = nx; normals[3*n+1] = ny; normals[3*n+2] = nz;

        float czv[4], pxv[4], pyv[4];
#pragma unroll
        for (int b = 0; b < 4; ++b) {
            const float* Vb = V + 16*b;
            float cx = Vb[0]*x + Vb[1]*y + Vb[2]*z  + Vb[3];
            float cy = Vb[4]*x + Vb[5]*y + Vb[6]*z  + Vb[7];
            float cz = Vb[8]*x + Vb[9]*y + Vb[10]*z + Vb[11];
            czv[b] = cz;
            float zc = fmaxf(cz, 1e-8f);
            pxv[b] = cx / zc;
            pyv[b] = cy / zc;
        }
        dsum = (double)(fabsf(czv[0]*o - czv[1]*o) + fabsf(czv[1]*o - czv[2]*o)
                      + fabsf(czv[2]*o - czv[3]*o));
        int pi = 0;
#pragma unroll
        for (int a = 0; a < 4; ++a) {
#pragma unroll
            for (int b2 = a + 1; b2 < 4; ++b2) {
                const float* F = Fm + 9*pi; ++pi;
                float x1 = pxv[a], y1 = pyv[a];
                float x2 = pxv[b2], y2 = pyv[b2];
                float l0 = F[0]*x1 + F[1]*y1 + F[2];
                float l1 = F[3]*x1 + F[4]*y1 + F[5];
                float l2 = F[6]*x1 + F[7]*y1 + F[8];
                float err = fabsf(x2*l0 + y2*l1 + l2);
                float nrm = sqrtf(l0*l0 + l1*l1) + 1e-8f;
                esum += (double)((err / nrm) * o);
            }
        }
    }
    dsum = waveReduce(dsum);
    esum = waveReduce(esum);
    __shared__ double sred[2][4];
    int lane = threadIdx.x & 63, w = threadIdx.x >> 6;
    if (lane == 0) { sred[0][w] = dsum; sred[1][w] = esum; }
    __syncthreads();
    if (threadIdx.x == 0) {
        double a0 = 0, a1 = 0;
        for (int k = 0; k < 4; ++k) { a0 += sred[0][k]; a1 += sred[1][k]; }
        atomicAdd(&acc[0], a0);
        atomicAdd(&acc[1], a1);
    }
}

// ---------- KNN seed: branchless top-10 distances over a strided sample ----------
__global__ void knn_seed(const float* __restrict__ pos,
                         float* __restrict__ seed_d2, int N) {
    int tid = threadIdx.x;
    int i = blockIdx.x * TPB + tid;
    int s = blockIdx.y;

    __shared__ float4 sp[SEED_PER];
    if (tid < SEED_PER) {
        int j = SEED_STRIDE * (SEED_PER * s + tid);
        sp[tid] = make_float4(pos[3*j], pos[3*j+1], pos[3*j+2], 0.f);
    }
    __syncthreads();

    float px = 0.f, py = 0.f, pz = 0.f;
    if (i < N) { px = pos[3*i]; py = pos[3*i+1]; pz = pos[3*i+2]; }

    float bd[KNN];
#pragma unroll
    for (int k = 0; k < KNN; ++k) bd[k] = 3.4e38f;

#pragma unroll 4
    for (int u = 0; u < SEED_PER; ++u) {
        int j = SEED_STRIDE * (SEED_PER * s + u);
        float4 q = sp[u];
        float dx = px - q.x, dy = py - q.y, dz = pz - q.z;
        float d2 = dx*dx + dy*dy + dz*dz;
        float cd = (j == i) ? 3.4e38f : d2;   // exclude self, branchless
#pragma unroll
        for (int k = 0; k < KNN; ++k) {       // branchless bubble insert
            float lo = fminf(bd[k], cd);
            cd = fmaxf(bd[k], cd);
            bd[k] = lo;
        }
    }
    if (i < N) {
#pragma unroll
        for (int k = 0; k < KNN; ++k)
            seed_d2[(size_t)(s*KNN + k) * N + i] = bd[k];
    }
}

// ---------- KNN threshold: merge seed lists -> T[i] = sample 10th smallest ----------
__global__ void knn_thresh(const float* __restrict__ seed_d2,
                           float* __restrict__ T, int N) {
    int i = blockIdx.x * TPB + threadIdx.x;
    if (i >= N) return;
    float bd[KNN];
#pragma unroll
    for (int k = 0; k < KNN; ++k) bd[k] = 3.4e38f;
#pragma unroll 4
    for (int t = 0; t < SEED_SPLITS * KNN; ++t) {
        float cd = seed_d2[(size_t)t * N + i];
#pragma unroll
        for (int k = 0; k < KNN; ++k) {
            float lo = fminf(bd[k], cd);
            cd = fmaxf(bd[k], cd);
            bd[k] = lo;
        }
    }
    T[i] = bd[KNN-1];
}

// ---------- KNN collect: append all j with d2 <= T[i] (no sorting in hot loop) ----------
__global__ void knn_collect(const float* __restrict__ pos,
                            const float* __restrict__ T,
                            int* __restrict__ cand,
                            unsigned char* __restrict__ cnt_buf, int N) {
    int tid = threadIdx.x;
    int s = blockIdx.y;            // split = one 256-wide j tile
    int j0 = s * TPB;
    int i0 = blockIdx.x * (TPB * IPT) + tid;
    int i1 = i0 + TPB;

    __shared__ float4 sp[TPB];
    {
        int j = j0 + tid;          // always < N (N % 256 == 0)
        sp[tid] = make_float4(pos[3*j], pos[3*j+1], pos[3*j+2], 0.f);
    }
    __syncthreads();

    bool v0 = i0 < N, v1 = i1 < N;
    float p0x = 0, p0y = 0, p0z = 0, p1x = 0, p1y = 0, p1z = 0;
    float T0 = -1.0f, T1 = -1.0f;
    if (v0) { p0x = pos[3*i0]; p0y = pos[3*i0+1]; p0z = pos[3*i0+2]; T0 = T[i0]; }
    if (v1) { p1x = pos[3*i1]; p1y = pos[3*i1+1]; p1z = pos[3*i1+2]; T1 = T[i1]; }

    int c0 = 0, c1 = 0;
    size_t b0 = ((size_t)s * N + i0) * CCAP;
    size_t b1 = ((size_t)s * N + i1) * CCAP;

#pragma unroll 8
    for (int jj = 0; jj < TPB; ++jj) {
        float4 q = sp[jj];
        int j = j0 + jj;
        float dx0 = p0x - q.x, dy0 = p0y - q.y, dz0 = p0z - q.z;
        float d0 = dx0*dx0 + dy0*dy0 + dz0*dz0;
        float dx1 = p1x - q.x, dy1 = p1y - q.y, dz1 = p1z - q.z;
        float d1 = dx1*dx1 + dy1*dy1 + dz1*dz1;
        if (d0 <= T0 && j != i0 && c0 < CCAP) { cand[b0 + c0] = j; ++c0; }
        if (d1 <= T1 && j != i1 && c1 < CCAP) { cand[b1 + c1] = j; ++c1; }
    }
    if (v0) cnt_buf[(size_t)s * N + i0] = (unsigned char)c0;
    if (v1) cnt_buf[(size_t)s * N + i1] = (unsigned char)c1;
}

// ---------- KNN final: merge candidates -> top-10 -> normal loss ----------
__global__ void knn_final(const float* __restrict__ pos,
                          const int* __restrict__ cand,
                          const unsigned char* __restrict__ cnt_buf,
                          const float* __restrict__ normals,
                          const float* __restrict__ opac,
                          double* __restrict__ acc, int N) {
    int i = blockIdx.x * TPB + threadIdx.x;
    double nsum = 0.0;
    if (i < N) {
        float px = pos[3*i], py = pos[3*i+1], pz = pos[3*i+2];
        float bd[KNN]; int bi[KNN];
#pragma unroll
        for (int k = 0; k < KNN; ++k) { bd[k] = 3.4e38f; bi[k] = -1; }
        for (int s = 0; s < CSPLITS; ++s) {
            int c = cnt_buf[(size_t)s * N + i];
            size_t base = ((size_t)s * N + i) * CCAP;
            for (int t = 0; t < c; ++t) {
                int j = cand[base + t];
                float dx = px - pos[3*j], dy = py - pos[3*j+1], dz = pz - pos[3*j+2];
                float d2 = dx*dx + dy*dy + dz*dz;
                if (d2 < bd[KNN-1]) {
                    float cd = d2; int ci = j;
#pragma unroll
                    for (int k = 0; k < KNN; ++k) {   // strict < keeps ascending-j tie order
                        bool sw = cd < bd[k];
                        float td = sw ? bd[k] : cd;  int ti = sw ? bi[k] : ci;
                        bd[k]    = sw ? cd   : bd[k]; bi[k] = sw ? ci   : bi[k];
                        cd = td; ci = ti;
                    }
                }
            }
        }
        float nx = normals[3*i], ny = normals[3*i+1], nz = normals[3*i+2];
        float ssum = 0.0f;
#pragma unroll
        for (int k = 0; k < KNN; ++k) {
            int j  = bi[k];
            int jj = j >= 0 ? j : 0;
            float wgt = j >= 0 ? 1.0f : 0.0f;
            float c = nx*normals[3*jj] + ny*normals[3*jj+1] + nz*normals[3*jj+2];
            ssum += wgt * (1.0f - c);
        }
        nsum = (double)(opac[i] * (ssum * 0.1f));
    }
    nsum = waveReduce(nsum);
    __shared__ double sred[4];
    int lane = threadIdx.x & 63, w = threadIdx.x >> 6;
    if (lane == 0) sred[w] = nsum;
    __syncthreads();
    if (threadIdx.x == 0) {
        double a = 0;
        for (int k = 0; k < 4; ++k) a += sred[k];
        atomicAdd(&acc[2], a);
    }
}

// ---------- finalize ----------
__global__ void finalize_kernel(const double* __restrict__ acc, float* __restrict__ out, int N) {
    if (threadIdx.x == 0 && blockIdx.x == 0) {
        double depth_loss  = acc[0] / (3.0 * (double)N);
        double epi_loss    = acc[1] / 6.0;
        double normal_loss = acc[2] / (double)N;
        out[0] = (float)(depth_loss + epi_loss + normal_loss);
    }
}

extern "C" void kernel_launch(void* const* d_in, const int* in_sizes, int n_in,
                              void* d_out, int out_size, void* d_ws, size_t ws_size,
                              hipStream_t stream) {
    const float* pos = (const float*)d_in[0];
    const float* rot = (const float*)d_in[1];
    const float* opa = (const float*)d_in[2];
    const float* V   = (const float*)d_in[3];
    float* out = (float*)d_out;

    int N = in_sizes[0] / 3;   // 12288

    char* w = (char*)d_ws;
    double* acc = (double*)w;
    float*  Fm  = (float*)(w + F_OFF);
    float*  nrm = (float*)(w + NRM_OFF);

    size_t t_off   = ((size_t)NRM_OFF + (size_t)N * 3 * 4 + 255) & ~(size_t)255;
    size_t cnt_off = (t_off + (size_t)N * 4 + 255) & ~(size_t)255;
    size_t buf_off = (cnt_off + (size_t)CSPLITS * N + 255) & ~(size_t)255;
    // union: seed_d2 (SEED_SPLITS*KNN*N*4 = 7.9 MB, used first)
    //        cand    (CSPLITS*N*CCAP*4  = 14.2 MB, used after knn_thresh)

    float*         T        = (float*)(w + t_off);
    unsigned char* cnt_buf  = (unsigned char*)(w + cnt_off);
    float*         seed_d2  = (float*)(w + buf_off);
    int*           cand     = (int*)(w + buf_off);

    int nBlocks = (N + TPB - 1) / TPB;                 // 48
    int cBlocks = (N + TPB * IPT - 1) / (TPB * IPT);   // 24

    setup_kernel<<<1, 64, 0, stream>>>(V, Fm, acc);
    perpoint_kernel<<<nBlocks, TPB, 0, stream>>>(pos, rot, opa, V, Fm, nrm, acc, N);
    knn_seed<<<dim3(nBlocks, SEED_SPLITS), TPB, 0, stream>>>(pos, seed_d2, N);
    knn_thresh<<<nBlocks, TPB, 0, stream>>>(seed_d2, T, N);
    knn_collect<<<dim3(cBlocks, CSPLITS), TPB, 0, stream>>>(pos, T, cand, cnt_buf, N);
    knn_final<<<nBlocks, TPB, 0, stream>>>(pos, cand, cnt_buf, nrm, opa, acc, N);
    finalize_kernel<<<1, 64, 0, stream>>>(acc, out, N);
}